// Round 9
// baseline (309.483 us; speedup 1.0000x reference)
//
#include <hip/hip_runtime.h>
#include <stdint.h>
#include <stddef.h>

typedef __attribute__((ext_vector_type(8))) short bf16x8_t;
typedef __attribute__((ext_vector_type(4))) float f32x4_t;
typedef __attribute__((ext_vector_type(16))) float f32x16_t;
typedef __attribute__((ext_vector_type(4))) unsigned int u32x4_t;
typedef __attribute__((ext_vector_type(2))) unsigned int u32x2_t;

__device__ __forceinline__ unsigned short f2bf(float f) {
  union { float f; unsigned int u; } x; x.f = f;
  unsigned int r = x.u + 0x7fffu + ((x.u >> 16) & 1u);
  return (unsigned short)(r >> 16);
}

__device__ __forceinline__ float e2(float x) { return __builtin_amdgcn_exp2f(x); }

// packed f32x2 -> bf16x2 (RNE), d[15:0]=cvt(lo), d[31:16]=cvt(hi)
__device__ __forceinline__ unsigned int cvtpk(float lo, float hi) {
  unsigned int d;
  asm("v_cvt_pk_bf16_f32 %0, %1, %2" : "=v"(d) : "v"(lo), "v"(hi));
  return d;
}
// after: a = {a.lo-lanes keep, hi-lanes <- b.lo-lanes}, b = {lo-lanes <- a.hi-lanes, hi keep}
__device__ __forceinline__ void plswap(unsigned int& a, unsigned int& b) {
  asm("v_permlane32_swap_b32 %0, %1" : "+v"(a), "+v"(b));
}

// async global->LDS, 16B per lane; LDS dest = wave-uniform base + lane*16
__device__ __forceinline__ void gload16(const void* g, void* l) {
  __builtin_amdgcn_global_load_lds(
      (const __attribute__((address_space(1))) void*)g,
      (__attribute__((address_space(3))) void*)l, 16, 0, 0);
}

// qscale = 1/sqrt(64) * log2(e)  (exp2-domain softmax)
#define QSCALE 0.18033688011112042f

// ---------------------------------------------------------------------------
// x: f32 -> bf16, 8 elems/thread
// ---------------------------------------------------------------------------
__global__ __launch_bounds__(256)
void f32_to_bf16(const float* __restrict__ in, unsigned short* __restrict__ out) {
  size_t i = ((size_t)blockIdx.x * 256 + threadIdx.x) * 8;
  f32x4_t a = *(const f32x4_t*)(in + i);
  f32x4_t b = *(const f32x4_t*)(in + i + 4);
  bf16x8_t o;
#pragma unroll
  for (int j = 0; j < 4; ++j) { o[j] = (short)f2bf(a[j]); o[j + 4] = (short)f2bf(b[j]); }
  *(bf16x8_t*)(out + i) = o;
}

// ---------------------------------------------------------------------------
// 3 weights f32 [1024][1024] -> bf16 transposed, concatenated [3072][1024]
// ---------------------------------------------------------------------------
__global__ __launch_bounds__(256)
void transpose_cvt3(const float* __restrict__ w0, const float* __restrict__ w1,
                    const float* __restrict__ w2, unsigned short* __restrict__ out) {
  __shared__ float t[32][33];
  const float* in = blockIdx.z == 0 ? w0 : (blockIdx.z == 1 ? w1 : w2);
  unsigned short* o = out + (size_t)blockIdx.z * 1024 * 1024;
  const int x = threadIdx.x & 31, y = threadIdx.x >> 5;  // 32 x 8
  const int bx = blockIdx.x * 32, by = blockIdx.y * 32;
#pragma unroll
  for (int i = 0; i < 32; i += 8)
    t[y + i][x] = in[(size_t)(by + y + i) * 1024 + bx + x];
  __syncthreads();
#pragma unroll
  for (int i = 0; i < 32; i += 8)
    o[(size_t)(bx + y + i) * 1024 + by + x] = f2bf(t[x][y + i]);
}

__global__ __launch_bounds__(256)
void transpose_cvt(const float* __restrict__ in, unsigned short* __restrict__ out) {
  __shared__ float t[32][33];
  const int x = threadIdx.x & 31, y = threadIdx.x >> 5;
  const int bx = blockIdx.x * 32, by = blockIdx.y * 32;
#pragma unroll
  for (int i = 0; i < 32; i += 8)
    t[y + i][x] = in[(size_t)(by + y + i) * 1024 + bx + x];
  __syncthreads();
#pragma unroll
  for (int i = 0; i < 32; i += 8)
    out[(size_t)(bx + y + i) * 1024 + by + x] = f2bf(t[x][y + i]);
}

// ---------------------------------------------------------------------------
// v bf16 [bh][2048][64] -> vt bf16 [bh][64][2048]
// ---------------------------------------------------------------------------
__global__ __launch_bounds__(256)
void transpose_v(const unsigned short* __restrict__ in, unsigned short* __restrict__ out) {
  __shared__ unsigned short t[64][65];
  const int bh = blockIdx.y;
  const int n0 = blockIdx.x * 64;
  const int c = threadIdx.x & 63, r4 = threadIdx.x >> 6;  // 64 x 4
#pragma unroll
  for (int i = 0; i < 64; i += 4)
    t[r4 + i][c] = in[((size_t)bh * 2048 + n0 + r4 + i) * 64 + c];
  __syncthreads();
#pragma unroll
  for (int i = 0; i < 64; i += 4)
    out[((size_t)bh * 64 + r4 + i) * 2048 + n0 + c] = t[c][r4 + i];
}

// ---------------------------------------------------------------------------
// 256x128-tile bf16 MFMA GEMM: C = A[M][K] * Bt[Nn][K]^T
// 512 threads = 8 waves (4 M-rows x 2 N-cols of 64x64 each), BK=32.
// LDS 48KB double-buffered; single-barrier pipelined K-loop; lb(512,4)
// -> 2 blocks/CU, 16 waves/CU.
// 1D grid, XCD-supertiled: xcd = bid&7 owns rowTiles row-blocks; col-blocks
// iterate outer within an XCD for B-panel L2 reuse.
// MODE 0: bf16 scatter into qkv[which][b,h,n,hd]; Q (which==0) scaled by QSCALE
// MODE 1: f32 [row][col] + f32 bias   (output projection)
// ---------------------------------------------------------------------------
template <int MODE>
__global__ __launch_bounds__(512, 4)
void gemm256(const unsigned short* __restrict__ A,
             const unsigned short* __restrict__ Bt,
             void* __restrict__ Cv,
             const float* __restrict__ bias,
             int M, int K, int Nn, int rowTiles) {
  __shared__ __align__(16) unsigned short As[2][256 * 32];  // 16KB per buf
  __shared__ __align__(16) unsigned short Bs[2][128 * 32];  // 8KB per buf

  const int tid = threadIdx.x;       // 0..511
  const int wave = tid >> 6;         // 0..7
  const int lane = tid & 63;
  const int l15 = lane & 15;
  const int lq = lane >> 4;

  const int bid = blockIdx.x;
  const int xcd = bid & 7, tb = bid >> 3;
  const int row0 = (xcd * rowTiles + (tb % rowTiles)) * 256;
  const int col0 = (tb / rowTiles) * 128;

  const int wr = (wave >> 1) * 64;   // 0,64,128,192
  const int wc = (wave & 1) * 64;    // 0,64

  f32x4_t acc[4][4];
#pragma unroll
  for (int m = 0; m < 4; ++m)
#pragma unroll
    for (int n = 0; n < 4; ++n) acc[m][n] = (f32x4_t)0.f;

  // staging: A = 1024 16B chunks (rows 256), B = 512 chunks (rows 128).
  // chunk p: row=p>>2, phys slot=p&3, logical slot=(p&3)^(row&3)
  const int pa0 = tid, pa1 = tid + 512, pb = tid;
  const int ra0 = pa0 >> 2, sa0 = (pa0 & 3) ^ (ra0 & 3);
  const int ra1 = pa1 >> 2, sa1 = (pa1 & 3) ^ (ra1 & 3);
  const int rb  = pb >> 2,  sb  = (pb & 3) ^ (rb & 3);

  const unsigned short* Ap0 = A + (size_t)(row0 + ra0) * K + sa0 * 8;
  const unsigned short* Ap1 = A + (size_t)(row0 + ra1) * K + sa1 * 8;
  const unsigned short* Bp0 = Bt + (size_t)(col0 + rb) * K + sb * 8;

  // prologue: stage K-step 0 into buf 0
  gload16(Ap0, (char*)As[0] + pa0 * 16);
  gload16(Ap1, (char*)As[0] + pa1 * 16);
  gload16(Bp0, (char*)Bs[0] + pb * 16);
  __syncthreads();

  const int NIT = K / 32;
  for (int it = 0; it < NIT; ++it) {
    const int cur = it & 1;
    if (it + 1 < NIT) {  // stage next K-step into the other buffer
      const int k0n = (it + 1) * 32;
      gload16(Ap0 + k0n, (char*)As[cur ^ 1] + pa0 * 16);
      gload16(Ap1 + k0n, (char*)As[cur ^ 1] + pa1 * 16);
      gload16(Bp0 + k0n, (char*)Bs[cur ^ 1] + pb * 16);
    }

    const char* Ac = (const char*)As[cur];
    const char* Bc = (const char*)Bs[cur];
    bf16x8_t af[4], bfr[4];
#pragma unroll
    for (int m = 0; m < 4; ++m) {
      int r = wr + m * 16 + l15;
      af[m] = *(const bf16x8_t*)(Ac + r * 64 + ((lq ^ (r & 3)) << 4));
    }
#pragma unroll
    for (int n = 0; n < 4; ++n) {
      int c = wc + n * 16 + l15;
      bfr[n] = *(const bf16x8_t*)(Bc + c * 64 + ((lq ^ (c & 3)) << 4));
    }
    __builtin_amdgcn_s_setprio(1);
#pragma unroll
    for (int m = 0; m < 4; ++m)
#pragma unroll
      for (int n = 0; n < 4; ++n)
        acc[m][n] = __builtin_amdgcn_mfma_f32_16x16x32_bf16(af[m], bfr[n], acc[m][n], 0, 0, 0);
    __builtin_amdgcn_s_setprio(0);

    __syncthreads();  // all waves done with buf[cur]; next-step loads drained
  }

  // C/D layout: col = lane&15, row = (lane>>4)*4 + j  (m89-verified)
#pragma unroll
  for (int m = 0; m < 4; ++m) {
    int rbase = row0 + wr + m * 16 + lq * 4;
#pragma unroll
    for (int n = 0; n < 4; ++n) {
      int col = col0 + wc + n * 16 + l15;
#pragma unroll
      for (int j = 0; j < 4; ++j) {
        int row = rbase + j;
        float v = acc[m][n][j];
        if constexpr (MODE == 0) {
          int which = col >> 10, cl = col & 1023;
          int b = row >> 11, nn = row & 2047, h = cl >> 6, hd = cl & 63;
          float s = (which == 0) ? QSCALE : 1.0f;
          ((unsigned short*)Cv)[(size_t)which * 8388608 +
                                (((size_t)(b * 16 + h)) * 2048 + nn) * 64 + hd] = f2bf(v * s);
        } else {
          ((float*)Cv)[(size_t)row * Nn + col] = v + bias[col];
        }
      }
    }
  }
}

// ---------------------------------------------------------------------------
// MFMA flash attention, 32x32x16 fragments, swapped operands, in-register P.
// qb (pre-scaled by QSCALE), kb: bf16 [bh][2048][64]; vtb: bf16 [bh][64][2048]
// Block: 512 thr = 8 waves; 256 q-rows/block (32/wave); KVBLK=128, dbuf.
// LDS 64KB -> 2 blocks/CU = 16 waves/CU; K/V tile shared by 8 waves.
// Softmax reductions use 4-way parallel trees (short fp dependency chains).
// Grid: 512 blocks 1D, XCD-swizzled so each bh's 8 q-blocks share an XCD.
// ---------------------------------------------------------------------------
__global__ __launch_bounds__(512, 4)
void attn_mfma(const unsigned short* __restrict__ qb,
               const unsigned short* __restrict__ kb,
               const unsigned short* __restrict__ vtb,
               unsigned short* __restrict__ ab) {
  // Ks: [128 key][8 slots x 8 hd], phys = slot ^ (key&7)
  // Vs: [64 hd][16 slots x 8 key], phys = (s&8)|((s&7)^(hd&7))
  __shared__ __align__(16) unsigned short Ks[2][8192];
  __shared__ __align__(16) unsigned short Vs[2][8192];

  const int tid = threadIdx.x, wave = tid >> 6, lane = tid & 63;
  const int l31 = lane & 31, hi = lane >> 5;

  // XCD swizzle: 512 blocks, xcd = bid & 7; 8 bh per XCD, 8 q-blocks per bh
  const int bid = blockIdx.x;
  const int xcd = bid & 7, w = bid >> 3;     // w in [0,64)
  const int bh = xcd * 8 + (w >> 3);
  const int q0 = (w & 7) * 256;

  // Q as B-fragments: col = q = l31, k = hi*8 + j; 4 k-steps over hd
  const unsigned short* qrow = qb + ((size_t)bh * 2048 + q0 + wave * 32 + l31) * 64;
  bf16x8_t qf[4];
#pragma unroll
  for (int ks = 0; ks < 4; ++ks)
    qf[ks] = *(const bf16x8_t*)(qrow + ks * 16 + hi * 8);

  f32x16_t O[2];
#pragma unroll
  for (int hb = 0; hb < 2; ++hb) O[hb] = (f32x16_t)0.f;
  float m_run = -1e30f, l_run = 0.f;

  // staging: 1024 16B chunks each for Ks/Vs per 16KB tile; thread stages
  // chunks {tid, tid+512}. Global source pre-inverse-swizzled.
  const unsigned short* kbase = kb + (size_t)bh * 2048 * 64;
  const unsigned short* vbase = vtb + (size_t)bh * 64 * 2048;
  int koff[2], voff[2];
#pragma unroll
  for (int i = 0; i < 2; ++i) {
    int c = tid + 512 * i;                       // [0,1024)
    int kr = c >> 3, kp = c & 7, kl = kp ^ (kr & 7);
    koff[i] = kr * 64 + kl * 8;
    int vr = c >> 4, vp = c & 15, vl = (vp & 8) | ((vp & 7) ^ (vr & 7));
    voff[i] = vr * 2048 + vl * 8;
  }

  // prologue: stage tile 0 into buf 0
#pragma unroll
  for (int i = 0; i < 2; ++i) {
    gload16(kbase + koff[i], (char*)Ks[0] + (tid + 512 * i) * 16);
    gload16(vbase + voff[i], (char*)Vs[0] + (tid + 512 * i) * 16);
  }
  __syncthreads();

  for (int t = 0; t < 16; ++t) {
    const int cur = t & 1;
    if (t < 15) {
      const unsigned short* kt = kbase + (size_t)(t + 1) * 8192;
      const unsigned short* vt = vbase + (t + 1) * 128;
#pragma unroll
      for (int i = 0; i < 2; ++i) {
        gload16(kt + koff[i], (char*)Ks[cur ^ 1] + (tid + 512 * i) * 16);
        gload16(vt + voff[i], (char*)Vs[cur ^ 1] + (tid + 512 * i) * 16);
      }
    }
    const char* Kc = (const char*)Ks[cur];
    const char* Vc = (const char*)Vs[cur];

    // S = K Q : C col = q (l31), row-in-block = (reg&3) + 8*(reg>>2) + 4*hi
    f32x16_t sacc[4];
#pragma unroll
    for (int kbk = 0; kbk < 4; ++kbk) sacc[kbk] = (f32x16_t)0.f;
    __builtin_amdgcn_s_setprio(1);
#pragma unroll
    for (int kbk = 0; kbk < 4; ++kbk) {
#pragma unroll
      for (int ks = 0; ks < 4; ++ks) {
        int key = kbk * 32 + l31;
        bf16x8_t kf = *(const bf16x8_t*)(Kc + key * 128 + (((ks * 2 + hi) ^ (key & 7)) << 4));
        sacc[kbk] = __builtin_amdgcn_mfma_f32_32x32x16_bf16(kf, qf[ks], sacc[kbk], 0, 0, 0);
      }
    }
    __builtin_amdgcn_s_setprio(0);

    // online softmax (exp2 domain); per-lane state for q-row = l31.
    // 4-way parallel max tree (short fp chains).
    float mk[4];
#pragma unroll
    for (int kbk = 0; kbk < 4; ++kbk) {
      float a0 = fmaxf(sacc[kbk][0], sacc[kbk][8]);
      float a1 = fmaxf(sacc[kbk][1], sacc[kbk][9]);
      float a2 = fmaxf(sacc[kbk][2], sacc[kbk][10]);
      float a3 = fmaxf(sacc[kbk][3], sacc[kbk][11]);
      float a4 = fmaxf(sacc[kbk][4], sacc[kbk][12]);
      float a5 = fmaxf(sacc[kbk][5], sacc[kbk][13]);
      float a6 = fmaxf(sacc[kbk][6], sacc[kbk][14]);
      float a7 = fmaxf(sacc[kbk][7], sacc[kbk][15]);
      a0 = fmaxf(a0, a4); a1 = fmaxf(a1, a5); a2 = fmaxf(a2, a6); a3 = fmaxf(a3, a7);
      mk[kbk] = fmaxf(fmaxf(a0, a1), fmaxf(a2, a3));
    }
    float mx = fmaxf(fmaxf(mk[0], mk[1]), fmaxf(mk[2], mk[3]));
    mx = fmaxf(mx, __shfl_xor(mx, 32));

    const float mn = fmaxf(m_run, mx);
    const float alpha = e2(m_run - mn);
    m_run = mn;
    l_run *= alpha;
#pragma unroll
    for (int hb = 0; hb < 2; ++hb)
#pragma unroll
      for (int r = 0; r < 16; ++r) O[hb][r] *= alpha;

    float psum = 0.f;
#pragma unroll
    for (int kbk = 0; kbk < 4; ++kbk) {
      float p[16];
#pragma unroll
      for (int r = 0; r < 16; ++r) p[r] = e2(sacc[kbk][r] - mn);
      // tree partial sum (depth ~4 instead of 16-chain)
      float s0 = p[0] + p[8],  s1 = p[1] + p[9],  s2 = p[2] + p[10], s3 = p[3] + p[11];
      float s4 = p[4] + p[12], s5 = p[5] + p[13], s6 = p[6] + p[14], s7 = p[7] + p[15];
      s0 += s4; s1 += s5; s2 += s6; s3 += s7;
      psum += (s0 + s1) + (s2 + s3);
      // P -> PV B-fragments via cvt_pk + permlane32_swap (T12)
#pragma unroll
      for (int u = 0; u < 2; ++u) {
        unsigned int a0 = cvtpk(p[8 * u + 0], p[8 * u + 1]);
        unsigned int b0 = cvtpk(p[8 * u + 4], p[8 * u + 5]);
        plswap(a0, b0);  // a0 = dword0, b0 = dword2
        unsigned int a1 = cvtpk(p[8 * u + 2], p[8 * u + 3]);
        unsigned int b1 = cvtpk(p[8 * u + 6], p[8 * u + 7]);
        plswap(a1, b1);  // a1 = dword1, b1 = dword3
        u32x4_t fw; fw[0] = a0; fw[1] = a1; fw[2] = b0; fw[3] = b1;
        bf16x8_t pfrag = *(bf16x8_t*)&fw;
        const int ks2 = kbk * 2 + u;
        __builtin_amdgcn_s_setprio(1);
#pragma unroll
        for (int hb = 0; hb < 2; ++hb) {
          int hd = hb * 32 + l31;
          int sl = ks2 * 2 + hi;
          bf16x8_t vf = *(const bf16x8_t*)(Vc + hd * 256 +
                          (((sl & 8) | ((sl & 7) ^ (hd & 7))) << 4));
          O[hb] = __builtin_amdgcn_mfma_f32_32x32x16_bf16(vf, pfrag, O[hb], 0, 0, 0);
        }
        __builtin_amdgcn_s_setprio(0);
      }
    }
    psum += __shfl_xor(psum, 32);
    l_run += psum;

    __syncthreads();
  }

  // epilogue: O col = q = l31; row = hd-in-block = (reg&3) + 8*(reg>>2) + 4*hi
  const int b = bh >> 4, h = bh & 15;
  const float inv = 1.f / l_run;
  const int row = q0 + wave * 32 + l31;
  unsigned short* op = ab + ((size_t)(b * 2048 + row)) * 1024 + h * 64;
#pragma unroll
  for (int hb = 0; hb < 2; ++hb)
#pragma unroll
    for (int tt = 0; tt < 4; ++tt) {
      u32x2_t d;
      d[0] = cvtpk(O[hb][4 * tt + 0] * inv, O[hb][4 * tt + 1] * inv);
      d[1] = cvtpk(O[hb][4 * tt + 2] * inv, O[hb][4 * tt + 3] * inv);
      *(u32x2_t*)(op + hb * 32 + tt * 8 + hi * 4) = d;
    }
}

// ---------------------------------------------------------------------------
extern "C" void kernel_launch(void* const* d_in, const int* in_sizes, int n_in,
                              void* d_out, int out_size, void* d_ws, size_t ws_size,
                              hipStream_t stream) {
  const float* x  = (const float*)d_in[0];
  const float* wq = (const float*)d_in[1];
  const float* wk = (const float*)d_in[2];
  const float* wv = (const float*)d_in[3];
  const float* wo = (const float*)d_in[4];
  const float* bo = (const float*)d_in[5];
  float* out = (float*)d_out;

  const size_t MB = 1ull << 20;
  char* ws = (char*)d_ws;
  unsigned short* xb  = (unsigned short*)(ws);            // 16.8 MB bf16 [8192][1024]
  unsigned short* ab  = xb;                               // reuse after x dead
  unsigned short* qkv = (unsigned short*)(ws + 17 * MB);  // 3 x 16.78 MB
  unsigned short* vtb = (unsigned short*)(ws + 68 * MB);  // bf16 [bh][64][2048]
  unsigned short* wT  = (unsigned short*)(ws + 85 * MB);  // 6 MB  [3072][1024]
  unsigned short* woT = (unsigned short*)(ws + 91 * MB);  // 2 MB

  const size_t X = 8388608;  // elems per q/k/v tensor

  const dim3 tb(256);
  f32_to_bf16<<<4096, tb, 0, stream>>>(x, xb);
  transpose_cvt3<<<dim3(32, 32, 3), tb, 0, stream>>>(wq, wk, wv, wT);
  transpose_cvt<<<dim3(32, 32), tb, 0, stream>>>(wo, woT);

  // fused QKV projection: N = 3072; grid = 8 xcd * 4 rowtiles(256) * 24 coltiles(128)
  gemm256<0><<<dim3(768), dim3(512), 0, stream>>>(xb, wT, (void*)qkv, nullptr,
                                                  8192, 1024, 3072, 4);

  transpose_v<<<dim3(32, 64), tb, 0, stream>>>(qkv + 2 * X, vtb);

  attn_mfma<<<dim3(512), dim3(512), 0, stream>>>(qkv, qkv + X, vtb, ab);

  // output projection: grid = 8 xcd * 4 rowtiles * 8 coltiles
  gemm256<1><<<dim3(256), dim3(512), 0, stream>>>(ab, woT, (void*)out, bo,
                                                  8192, 1024, 1024, 4);
}

// Round 12
// 287.100 us; speedup vs baseline: 1.0780x; 1.0780x over previous
//
#include <hip/hip_runtime.h>
#include <stdint.h>
#include <stddef.h>

typedef __attribute__((ext_vector_type(8))) short bf16x8_t;
typedef __attribute__((ext_vector_type(4))) float f32x4_t;
typedef __attribute__((ext_vector_type(16))) float f32x16_t;
typedef __attribute__((ext_vector_type(4))) unsigned int u32x4_t;
typedef __attribute__((ext_vector_type(2))) unsigned int u32x2_t;

__device__ __forceinline__ unsigned short f2bf(float f) {
  union { float f; unsigned int u; } x; x.f = f;
  unsigned int r = x.u + 0x7fffu + ((x.u >> 16) & 1u);
  return (unsigned short)(r >> 16);
}

__device__ __forceinline__ float e2(float x) { return __builtin_amdgcn_exp2f(x); }

// packed f32x2 -> bf16x2 (RNE), d[15:0]=cvt(lo), d[31:16]=cvt(hi)
__device__ __forceinline__ unsigned int cvtpk(float lo, float hi) {
  unsigned int d;
  asm("v_cvt_pk_bf16_f32 %0, %1, %2" : "=v"(d) : "v"(lo), "v"(hi));
  return d;
}
// after: a = {a.lo-lanes keep, hi-lanes <- b.lo-lanes}, b = {lo-lanes <- a.hi-lanes, hi keep}
__device__ __forceinline__ void plswap(unsigned int& a, unsigned int& b) {
  asm("v_permlane32_swap_b32 %0, %1" : "+v"(a), "+v"(b));
}

// async global->LDS, 16B per lane; LDS dest = wave-uniform base + lane*16
__device__ __forceinline__ void gload16(const void* g, void* l) {
  __builtin_amdgcn_global_load_lds(
      (const __attribute__((address_space(1))) void*)g,
      (__attribute__((address_space(3))) void*)l, 16, 0, 0);
}

// qscale = 1/sqrt(64) * log2(e)  (exp2-domain softmax)
#define QSCALE 0.18033688011112042f

// ---------------------------------------------------------------------------
// x: f32 -> bf16, 8 elems/thread
// ---------------------------------------------------------------------------
__global__ __launch_bounds__(256)
void f32_to_bf16(const float* __restrict__ in, unsigned short* __restrict__ out) {
  size_t i = ((size_t)blockIdx.x * 256 + threadIdx.x) * 8;
  f32x4_t a = *(const f32x4_t*)(in + i);
  f32x4_t b = *(const f32x4_t*)(in + i + 4);
  bf16x8_t o;
#pragma unroll
  for (int j = 0; j < 4; ++j) { o[j] = (short)f2bf(a[j]); o[j + 4] = (short)f2bf(b[j]); }
  *(bf16x8_t*)(out + i) = o;
}

// ---------------------------------------------------------------------------
// 4 weights f32 [1024][1024] -> bf16 transposed; wq/wk/wv -> wT (concat), wo -> woT
// ---------------------------------------------------------------------------
__global__ __launch_bounds__(256)
void transpose_cvt4(const float* __restrict__ w0, const float* __restrict__ w1,
                    const float* __restrict__ w2, const float* __restrict__ w3,
                    unsigned short* __restrict__ wT, unsigned short* __restrict__ woT) {
  __shared__ float t[32][33];
  const int z = blockIdx.z;
  const float* in = (z == 0) ? w0 : (z == 1) ? w1 : (z == 2) ? w2 : w3;
  unsigned short* o = (z < 3) ? (wT + (size_t)z * 1024 * 1024) : woT;
  const int x = threadIdx.x & 31, y = threadIdx.x >> 5;  // 32 x 8
  const int bx = blockIdx.x * 32, by = blockIdx.y * 32;
#pragma unroll
  for (int i = 0; i < 32; i += 8)
    t[y + i][x] = in[(size_t)(by + y + i) * 1024 + bx + x];
  __syncthreads();
#pragma unroll
  for (int i = 0; i < 32; i += 8)
    o[(size_t)(bx + y + i) * 1024 + by + x] = f2bf(t[x][y + i]);
}

// ---------------------------------------------------------------------------
// v bf16 [bh][2048][64] -> vt bf16 [bh][64][2048]
// ---------------------------------------------------------------------------
__global__ __launch_bounds__(256)
void transpose_v(const unsigned short* __restrict__ in, unsigned short* __restrict__ out) {
  __shared__ unsigned short t[64][65];
  const int bh = blockIdx.y;
  const int n0 = blockIdx.x * 64;
  const int c = threadIdx.x & 63, r4 = threadIdx.x >> 6;  // 64 x 4
#pragma unroll
  for (int i = 0; i < 64; i += 4)
    t[r4 + i][c] = in[((size_t)bh * 2048 + n0 + r4 + i) * 64 + c];
  __syncthreads();
#pragma unroll
  for (int i = 0; i < 64; i += 4)
    out[((size_t)bh * 64 + r4 + i) * 2048 + n0 + c] = t[c][r4 + i];
}

// ---------------------------------------------------------------------------
// 256x128-tile bf16 MFMA GEMM, BK=64: C = A[M][K] * Bt[Nn][K]^T
// 512 threads = 8 waves (4M x 2N of 64x64 each). LDS 96KB dynamic, double-
// buffered; 2-phase single-barrier K-loop (stage t+1, compute t, barrier).
// Rows are 128B = 8 x 16B slots, phys = slot ^ (row&7) (XOR involution).
// 1D grid, XCD-supertiled: xcd = bid&7 owns rowTiles row-blocks; col-blocks
// iterate outer within an XCD for B-panel L2 reuse.
// MODE 0: bf16 scatter into qkv[which][b,h,n,hd]; Q (which==0) scaled by QSCALE
// MODE 1: f32 [row][col] + f32 bias   (output projection)
// ---------------------------------------------------------------------------
template <int MODE>
__global__ __launch_bounds__(512, 1)
void gemm256(const unsigned short* __restrict__ A,
             const unsigned short* __restrict__ Bt,
             void* __restrict__ Cv,
             const float* __restrict__ bias,
             int M, int K, int Nn, int rowTiles) {
  extern __shared__ __align__(16) char smem[];
  // layout: [A0 32K | A1 32K | B0 16K | B1 16K]
  char* Abuf0 = smem;
  char* Abuf1 = smem + 32768;
  char* Bbuf0 = smem + 65536;
  char* Bbuf1 = smem + 81920;

  const int tid = threadIdx.x;       // 0..511
  const int wave = tid >> 6;         // 0..7
  const int lane = tid & 63;
  const int l15 = lane & 15;
  const int lq = lane >> 4;

  const int bid = blockIdx.x;
  const int xcd = bid & 7, tb = bid >> 3;
  const int row0 = (xcd * rowTiles + (tb % rowTiles)) * 256;
  const int col0 = (tb / rowTiles) * 128;

  const int wr = (wave >> 1) * 64;   // 0,64,128,192
  const int wc = (wave & 1) * 64;    // 0,64

  f32x4_t acc[4][4];
#pragma unroll
  for (int m = 0; m < 4; ++m)
#pragma unroll
    for (int n = 0; n < 4; ++n) acc[m][n] = (f32x4_t)0.f;

  // staging: A = 2048 16B chunks (256 rows x 8 slots) -> 4/thread;
  //          B = 1024 chunks (128 rows x 8 slots)     -> 2/thread.
  // chunk c: row = c>>3, phys slot = c&7, logical slot = (c&7)^(row&7)
  const unsigned short* Apt[4];
  const unsigned short* Bpt[2];
#pragma unroll
  for (int i = 0; i < 4; ++i) {
    int c = tid + 512 * i;
    int r = c >> 3, s = (c & 7) ^ (r & 7);
    Apt[i] = A + (size_t)(row0 + r) * K + s * 8;
  }
#pragma unroll
  for (int i = 0; i < 2; ++i) {
    int c = tid + 512 * i;
    int r = c >> 3, s = (c & 7) ^ (r & 7);
    Bpt[i] = Bt + (size_t)(col0 + r) * K + s * 8;
  }

  // prologue: stage K-step 0 into buf 0
#pragma unroll
  for (int i = 0; i < 4; ++i) gload16(Apt[i], Abuf0 + (tid + 512 * i) * 16);
#pragma unroll
  for (int i = 0; i < 2; ++i) gload16(Bpt[i], Bbuf0 + (tid + 512 * i) * 16);
  __syncthreads();

  const int NIT = K >> 6;
  for (int it = 0; it < NIT; ++it) {
    const int cur = it & 1;
    char* Ac = cur ? Abuf1 : Abuf0;
    char* Bc = cur ? Bbuf1 : Bbuf0;
    if (it + 1 < NIT) {  // stage next K-step into the other buffer
      const int k0n = (it + 1) * 64;
      char* An = cur ? Abuf0 : Abuf1;
      char* Bn = cur ? Bbuf0 : Bbuf1;
#pragma unroll
      for (int i = 0; i < 4; ++i) gload16(Apt[i] + k0n, An + (tid + 512 * i) * 16);
#pragma unroll
      for (int i = 0; i < 2; ++i) gload16(Bpt[i] + k0n, Bn + (tid + 512 * i) * 16);
    }

#pragma unroll
    for (int ks2 = 0; ks2 < 2; ++ks2) {
      bf16x8_t af[4], bfr[4];
#pragma unroll
      for (int m = 0; m < 4; ++m) {
        int r = wr + m * 16 + l15;
        af[m] = *(const bf16x8_t*)(Ac + r * 128 + (((ks2 * 4 + lq) ^ (r & 7)) << 4));
      }
#pragma unroll
      for (int n = 0; n < 4; ++n) {
        int c = wc + n * 16 + l15;
        bfr[n] = *(const bf16x8_t*)(Bc + c * 128 + (((ks2 * 4 + lq) ^ (c & 7)) << 4));
      }
#pragma unroll
      for (int m = 0; m < 4; ++m)
#pragma unroll
        for (int n = 0; n < 4; ++n)
          acc[m][n] = __builtin_amdgcn_mfma_f32_16x16x32_bf16(af[m], bfr[n], acc[m][n], 0, 0, 0);
    }

    __syncthreads();  // all waves done with buf[cur]; next-step loads drained
  }

  // C/D layout: col = lane&15, row = (lane>>4)*4 + j  (m89-verified)
#pragma unroll
  for (int m = 0; m < 4; ++m) {
    int rbase = row0 + wr + m * 16 + lq * 4;
#pragma unroll
    for (int n = 0; n < 4; ++n) {
      int col = col0 + wc + n * 16 + l15;
#pragma unroll
      for (int j = 0; j < 4; ++j) {
        int row = rbase + j;
        float v = acc[m][n][j];
        if constexpr (MODE == 0) {
          int which = col >> 10, cl = col & 1023;
          int b = row >> 11, nn = row & 2047, h = cl >> 6, hd = cl & 63;
          float s = (which == 0) ? QSCALE : 1.0f;
          ((unsigned short*)Cv)[(size_t)which * 8388608 +
                                (((size_t)(b * 16 + h)) * 2048 + nn) * 64 + hd] = f2bf(v * s);
        } else {
          ((float*)Cv)[(size_t)row * Nn + col] = v + bias[col];
        }
      }
    }
  }
}

// ---------------------------------------------------------------------------
// MFMA flash attention, 32x32x16 fragments, swapped operands, in-register P.
// qb (pre-scaled by QSCALE), kb: bf16 [bh][2048][64]; vtb: bf16 [bh][64][2048]
// Block: 512 thr = 8 waves; 256 q-rows/block (32/wave); KVBLK=128, dbuf.
// LDS 64KB -> 2 blocks/CU = 16 waves/CU; K/V tile shared by 8 waves.
// Softmax reductions use 4-way parallel trees (short fp chains). No setprio
// (round-9 A/B: setprio on this lockstep schedule regressed).
// Grid: 512 blocks 1D, XCD-swizzled so each bh's 8 q-blocks share an XCD.
// ---------------------------------------------------------------------------
__global__ __launch_bounds__(512, 4)
void attn_mfma(const unsigned short* __restrict__ qb,
               const unsigned short* __restrict__ kb,
               const unsigned short* __restrict__ vtb,
               unsigned short* __restrict__ ab) {
  // Ks: [128 key][8 slots x 8 hd], phys = slot ^ (key&7)
  // Vs: [64 hd][16 slots x 8 key], phys = (s&8)|((s&7)^(hd&7))
  __shared__ __align__(16) unsigned short Ks[2][8192];
  __shared__ __align__(16) unsigned short Vs[2][8192];

  const int tid = threadIdx.x, wave = tid >> 6, lane = tid & 63;
  const int l31 = lane & 31, hi = lane >> 5;

  // XCD swizzle: 512 blocks, xcd = bid & 7; 8 bh per XCD, 8 q-blocks per bh
  const int bid = blockIdx.x;
  const int xcd = bid & 7, w = bid >> 3;     // w in [0,64)
  const int bh = xcd * 8 + (w >> 3);
  const int q0 = (w & 7) * 256;

  // Q as B-fragments: col = q = l31, k = hi*8 + j; 4 k-steps over hd
  const unsigned short* qrow = qb + ((size_t)bh * 2048 + q0 + wave * 32 + l31) * 64;
  bf16x8_t qf[4];
#pragma unroll
  for (int ks = 0; ks < 4; ++ks)
    qf[ks] = *(const bf16x8_t*)(qrow + ks * 16 + hi * 8);

  f32x16_t O[2];
#pragma unroll
  for (int hb = 0; hb < 2; ++hb) O[hb] = (f32x16_t)0.f;
  float m_run = -1e30f, l_run = 0.f;

  // staging: 1024 16B chunks each for Ks/Vs per 16KB tile; thread stages
  // chunks {tid, tid+512}. Global source pre-inverse-swizzled.
  const unsigned short* kbase = kb + (size_t)bh * 2048 * 64;
  const unsigned short* vbase = vtb + (size_t)bh * 64 * 2048;
  int koff[2], voff[2];
#pragma unroll
  for (int i = 0; i < 2; ++i) {
    int c = tid + 512 * i;                       // [0,1024)
    int kr = c >> 3, kp = c & 7, kl = kp ^ (kr & 7);
    koff[i] = kr * 64 + kl * 8;
    int vr = c >> 4, vp = c & 15, vl = (vp & 8) | ((vp & 7) ^ (vr & 7));
    voff[i] = vr * 2048 + vl * 8;
  }

  // prologue: stage tile 0 into buf 0
#pragma unroll
  for (int i = 0; i < 2; ++i) {
    gload16(kbase + koff[i], (char*)Ks[0] + (tid + 512 * i) * 16);
    gload16(vbase + voff[i], (char*)Vs[0] + (tid + 512 * i) * 16);
  }
  __syncthreads();

  for (int t = 0; t < 16; ++t) {
    const int cur = t & 1;
    if (t < 15) {
      const unsigned short* kt = kbase + (size_t)(t + 1) * 8192;
      const unsigned short* vt = vbase + (t + 1) * 128;
#pragma unroll
      for (int i = 0; i < 2; ++i) {
        gload16(kt + koff[i], (char*)Ks[cur ^ 1] + (tid + 512 * i) * 16);
        gload16(vt + voff[i], (char*)Vs[cur ^ 1] + (tid + 512 * i) * 16);
      }
    }
    const char* Kc = (const char*)Ks[cur];
    const char* Vc = (const char*)Vs[cur];

    // S = K Q : C col = q (l31), row-in-block = (reg&3) + 8*(reg>>2) + 4*hi
    f32x16_t sacc[4];
#pragma unroll
    for (int kbk = 0; kbk < 4; ++kbk) sacc[kbk] = (f32x16_t)0.f;
#pragma unroll
    for (int kbk = 0; kbk < 4; ++kbk) {
#pragma unroll
      for (int ks = 0; ks < 4; ++ks) {
        int key = kbk * 32 + l31;
        bf16x8_t kf = *(const bf16x8_t*)(Kc + key * 128 + (((ks * 2 + hi) ^ (key & 7)) << 4));
        sacc[kbk] = __builtin_amdgcn_mfma_f32_32x32x16_bf16(kf, qf[ks], sacc[kbk], 0, 0, 0);
      }
    }

    // online softmax (exp2 domain); per-lane state for q-row = l31.
    // 4-way parallel max tree (short fp chains).
    float mk[4];
#pragma unroll
    for (int kbk = 0; kbk < 4; ++kbk) {
      float a0 = fmaxf(sacc[kbk][0], sacc[kbk][8]);
      float a1 = fmaxf(sacc[kbk][1], sacc[kbk][9]);
      float a2 = fmaxf(sacc[kbk][2], sacc[kbk][10]);
      float a3 = fmaxf(sacc[kbk][3], sacc[kbk][11]);
      float a4 = fmaxf(sacc[kbk][4], sacc[kbk][12]);
      float a5 = fmaxf(sacc[kbk][5], sacc[kbk][13]);
      float a6 = fmaxf(sacc[kbk][6], sacc[kbk][14]);
      float a7 = fmaxf(sacc[kbk][7], sacc[kbk][15]);
      a0 = fmaxf(a0, a4); a1 = fmaxf(a1, a5); a2 = fmaxf(a2, a6); a3 = fmaxf(a3, a7);
      mk[kbk] = fmaxf(fmaxf(a0, a1), fmaxf(a2, a3));
    }
    float mx = fmaxf(fmaxf(mk[0], mk[1]), fmaxf(mk[2], mk[3]));
    mx = fmaxf(mx, __shfl_xor(mx, 32));

    const float mn = fmaxf(m_run, mx);
    const float alpha = e2(m_run - mn);
    m_run = mn;
    l_run *= alpha;
#pragma unroll
    for (int hb = 0; hb < 2; ++hb)
#pragma unroll
      for (int r = 0; r < 16; ++r) O[hb][r] *= alpha;

    float psum = 0.f;
#pragma unroll
    for (int kbk = 0; kbk < 4; ++kbk) {
      float p[16];
#pragma unroll
      for (int r = 0; r < 16; ++r) p[r] = e2(sacc[kbk][r] - mn);
      // tree partial sum (depth ~4 instead of 16-chain)
      float s0 = p[0] + p[8],  s1 = p[1] + p[9],  s2 = p[2] + p[10], s3 = p[3] + p[11];
      float s4 = p[4] + p[12], s5 = p[5] + p[13], s6 = p[6] + p[14], s7 = p[7] + p[15];
      s0 += s4; s1 += s5; s2 += s6; s3 += s7;
      psum += (s0 + s1) + (s2 + s3);
      // P -> PV B-fragments via cvt_pk + permlane32_swap (T12)
#pragma unroll
      for (int u = 0; u < 2; ++u) {
        unsigned int a0 = cvtpk(p[8 * u + 0], p[8 * u + 1]);
        unsigned int b0 = cvtpk(p[8 * u + 4], p[8 * u + 5]);
        plswap(a0, b0);  // a0 = dword0, b0 = dword2
        unsigned int a1 = cvtpk(p[8 * u + 2], p[8 * u + 3]);
        unsigned int b1 = cvtpk(p[8 * u + 6], p[8 * u + 7]);
        plswap(a1, b1);  // a1 = dword1, b1 = dword3
        u32x4_t fw; fw[0] = a0; fw[1] = a1; fw[2] = b0; fw[3] = b1;
        bf16x8_t pfrag = *(bf16x8_t*)&fw;
        const int ks2 = kbk * 2 + u;
#pragma unroll
        for (int hb = 0; hb < 2; ++hb) {
          int hd = hb * 32 + l31;
          int sl = ks2 * 2 + hi;
          bf16x8_t vf = *(const bf16x8_t*)(Vc + hd * 256 +
                          (((sl & 8) | ((sl & 7) ^ (hd & 7))) << 4));
          O[hb] = __builtin_amdgcn_mfma_f32_32x32x16_bf16(vf, pfrag, O[hb], 0, 0, 0);
        }
      }
    }
    psum += __shfl_xor(psum, 32);
    l_run += psum;

    __syncthreads();
  }

  // epilogue: O col = q = l31; row = hd-in-block = (reg&3) + 8*(reg>>2) + 4*hi
  const int b = bh >> 4, h = bh & 15;
  const float inv = 1.f / l_run;
  const int row = q0 + wave * 32 + l31;
  unsigned short* op = ab + ((size_t)(b * 2048 + row)) * 1024 + h * 64;
#pragma unroll
  for (int hb = 0; hb < 2; ++hb)
#pragma unroll
    for (int tt = 0; tt < 4; ++tt) {
      u32x2_t d;
      d[0] = cvtpk(O[hb][4 * tt + 0] * inv, O[hb][4 * tt + 1] * inv);
      d[1] = cvtpk(O[hb][4 * tt + 2] * inv, O[hb][4 * tt + 3] * inv);
      *(u32x2_t*)(op + hb * 32 + tt * 8 + hi * 4) = d;
    }
}

// ---------------------------------------------------------------------------
extern "C" void kernel_launch(void* const* d_in, const int* in_sizes, int n_in,
                              void* d_out, int out_size, void* d_ws, size_t ws_size,
                              hipStream_t stream) {
  const float* x  = (const float*)d_in[0];
  const float* wq = (const float*)d_in[1];
  const float* wk = (const float*)d_in[2];
  const float* wv = (const float*)d_in[3];
  const float* wo = (const float*)d_in[4];
  const float* bo = (const float*)d_in[5];
  float* out = (float*)d_out;

  const size_t MB = 1ull << 20;
  char* ws = (char*)d_ws;
  unsigned short* xb  = (unsigned short*)(ws);            // 16.8 MB bf16 [8192][1024]
  unsigned short* ab  = xb;                               // reuse after x dead
  unsigned short* qkv = (unsigned short*)(ws + 17 * MB);  // 3 x 16.78 MB
  unsigned short* vtb = (unsigned short*)(ws + 68 * MB);  // bf16 [bh][64][2048]
  unsigned short* wT  = (unsigned short*)(ws + 85 * MB);  // 6 MB  [3072][1024]
  unsigned short* woT = (unsigned short*)(ws + 91 * MB);  // 2 MB

  const size_t X = 8388608;  // elems per q/k/v tensor

  const dim3 tb(256);
  f32_to_bf16<<<4096, tb, 0, stream>>>(x, xb);
  transpose_cvt4<<<dim3(32, 32, 4), tb, 0, stream>>>(wq, wk, wv, wo, wT, woT);

  // fused QKV projection: N = 3072; grid = 8 xcd * 4 rowtiles(256) * 24 coltiles(128)
  gemm256<0><<<dim3(768), dim3(512), 98304, stream>>>(xb, wT, (void*)qkv, nullptr,
                                                      8192, 1024, 3072, 4);

  transpose_v<<<dim3(32, 64), tb, 0, stream>>>(qkv + 2 * X, vtb);

  attn_mfma<<<dim3(512), dim3(512), 0, stream>>>(qkv, qkv + X, vtb, ab);

  // output projection: grid = 8 xcd * 4 rowtiles * 8 coltiles
  gemm256<1><<<dim3(256), dim3(512), 98304, stream>>>(ab, woT, (void*)out, bo,
                                                      8192, 1024, 1024, 4);
}